// Round 1
// 106.350 us; speedup vs baseline: 1.0325x; 1.0325x over previous
//
#include <hip/hip_runtime.h>
#include <hip/hip_bf16.h>

// Correlation loss, fully folded into bf16 MFMA.
// r6: tile-level symmetry (36 of 64 32x32 regions, off-diag weight 2) +
// 32x32x16 MFMA shape: 3 MFMAs per region (2 main K-halves + 1 extras)
// instead of 8 16x16-shaped ones. C/D layout irrelevant (we sum |g| over
// all regs); K-permutation consistent between A and B frags so the gram
// is exact. Staging identical to r5 (numerics preserved).

#define PSZ  256
#define IMG  512
#define IMG2 (IMG * IMG)
#define XSTR 40          // ushorts per xs row = 80 B (16B-aligned; b128 2-way max)

typedef __attribute__((ext_vector_type(8))) short short8;
typedef __attribute__((ext_vector_type(16))) float f32x16;

static __device__ __forceinline__ unsigned short f2bf(float v) {
    union { __hip_bfloat16 b; unsigned short u; } cv;
    cv.b = __float2bfloat16(v);
    return cv.u;
}
static __device__ __forceinline__ float bf2f(unsigned short u) {
    union { unsigned int u; float f; } cv;
    cv.u = ((unsigned int)u) << 16;
    return cv.f;
}

// packed bf16 x -> -2*x (sign flip + exponent+1; no carry since 0 <= x < 2)
static __device__ __forceinline__ short8 neg2(uint4 u) {
    u.x = (u.x ^ 0x80008000u) + 0x00800080u;
    u.y = (u.y ^ 0x80008000u) + 0x00800080u;
    u.z = (u.z ^ 0x80008000u) + 0x00800080u;
    u.w = (u.w ^ 0x80008000u) + 0x00800080u;
    return *(short8*)&u;
}

static __device__ __forceinline__ float abs_sum16(f32x16 g) {
    float s0 = fabsf(g[0])  + fabsf(g[1]);
    float s1 = fabsf(g[2])  + fabsf(g[3]);
    float s2 = fabsf(g[4])  + fabsf(g[5]);
    float s3 = fabsf(g[6])  + fabsf(g[7]);
    float s4 = fabsf(g[8])  + fabsf(g[9]);
    float s5 = fabsf(g[10]) + fabsf(g[11]);
    float s6 = fabsf(g[12]) + fabsf(g[13]);
    float s7 = fabsf(g[14]) + fabsf(g[15]);
    s0 += s1; s2 += s3; s4 += s5; s6 += s7;
    s0 += s2; s4 += s6;
    return s0 + s4;
}

__global__ __launch_bounds__(256, 4)
void corr_loss_kernel(const float* __restrict__ msi,
                      const float* __restrict__ he,
                      const int* __restrict__ i_idx,
                      const int* __restrict__ j_idx,
                      float* __restrict__ partial)
{
    __shared__ __align__(16) unsigned short xs[PSZ * XSTR];  // m*bf16(msi) [p][k]
    __shared__ __align__(16) unsigned short eA[PSZ * 8];     // extras A-frag / column
    __shared__ __align__(16) unsigned short eB[PSZ * 8];     // extras B-frag / column
    __shared__ float red[4];

    const int b = blockIdx.x;
    const int t = threadIdx.x;
    const int i0 = i_idx[b], j0 = j_idx[b];

    // ---- stage column p = t: prefetch ALL loads, then convert (as r5) ----
    {
        const int r = t >> 4, c = t & 15;
        const float* hp = he + (size_t)(i0 + r) * IMG + (j0 + c);
        const float* mp = msi + (size_t)(i0 + r) * IMG + (j0 + c);

        float h0 = hp[0], h1 = hp[IMG2], h2 = hp[2 * IMG2];
        float v[32];
#pragma unroll
        for (int ch = 0; ch < 32; ++ch) v[ch] = mp[(size_t)ch * IMG2];

        const float mf = (h0 + h1 + h2 >= 0.05f) ? 1.f : 0.f;   // mask: exact fp32
        const unsigned short hb0 = f2bf(h0 * mf), hb1 = f2bf(h1 * mf), hb2 = f2bf(h2 * mf);
        const float hr0 = bf2f(hb0), hr1 = bf2f(hb1), hr2 = bf2f(hb2);
        const float sh = hr0 * hr0 + hr1 * hr1 + hr2 * hr2;

        float sm = 0.f;
#pragma unroll
        for (int g = 0; g < 4; ++g) {
            unsigned int pk[4];
#pragma unroll
            for (int k = 0; k < 4; ++k) {
                unsigned short lo = f2bf(v[g * 8 + 2 * k]     * mf);
                unsigned short hi = f2bf(v[g * 8 + 2 * k + 1] * mf);
                float fl = bf2f(lo), fh = bf2f(hi);
                sm = fmaf(fl, fl, sm);
                sm = fmaf(fh, fh, sm);
                pk[k] = (unsigned int)lo | ((unsigned int)hi << 16);
            }
            *(uint4*)&xs[t * XSTR + g * 8] = make_uint4(pk[0], pk[1], pk[2], pk[3]);
        }
        const float s = sm - sh;                 // masked already (m^2 = m)
        const unsigned short shi = f2bf(s);
        const unsigned short slo = f2bf(s - bf2f(shi));
        const unsigned short mb  = (mf != 0.f) ? (unsigned short)0x3F80 : (unsigned short)0;
        const unsigned short d0  = f2bf(2.f * hr0);   // exact: exponent+1
        const unsigned short d1  = f2bf(2.f * hr1);
        const unsigned short d2  = f2bf(2.f * hr2);
        // eA = {2h0, 2h1, 2h2, s_hi, s_lo, m, m, 0}
        *(uint4*)&eA[t * 8] = make_uint4(
            (unsigned)d0 | ((unsigned)d1 << 16),
            (unsigned)d2 | ((unsigned)shi << 16),
            (unsigned)slo | ((unsigned)mb << 16),
            (unsigned)mb);
        // eB = {h0, h1, h2, m, m, s_hi, s_lo, 0}
        *(uint4*)&eB[t * 8] = make_uint4(
            (unsigned)hb0 | ((unsigned)hb1 << 16),
            (unsigned)hb2 | ((unsigned)mb << 16),
            (unsigned)mb | ((unsigned)shi << 16),
            (unsigned)slo);
    }
    __syncthreads();

    // ---- 8x8 grid of 32x32 regions; wave w owns rows {w, 7-w} = 9 regions ----
    const int lane = t & 63, w = t >> 6;
    const int row = lane & 31, half = lane >> 5;   // 32x32x16: k = half*8 + elem
    const int rA = w, rB = 7 - w;
    const short8 zfrag = {0, 0, 0, 0, 0, 0, 0, 0};
    const f32x16 zacc = {0.f, 0.f, 0.f, 0.f, 0.f, 0.f, 0.f, 0.f,
                         0.f, 0.f, 0.f, 0.f, 0.f, 0.f, 0.f, 0.f};

    // hoist A-frags for the wave's two row-tiles; on-the-fly x~ -> -2*x~
    const int gA = (rA << 5) + row;
    const int gB = (rB << 5) + row;
    const short8 AmA0 = neg2(*(const uint4*)&xs[gA * XSTR + (half << 3)]);
    const short8 AmA1 = neg2(*(const uint4*)&xs[gA * XSTR + 16 + (half << 3)]);
    const short8 AhA  = half ? zfrag : *(const short8*)&eA[gA << 3];
    const short8 AmB0 = neg2(*(const uint4*)&xs[gB * XSTR + (half << 3)]);
    const short8 AmB1 = neg2(*(const uint4*)&xs[gB * XSTR + 16 + (half << 3)]);
    const short8 AhB  = half ? zfrag : *(const short8*)&eA[gB << 3];

    float acc1 = 0.f;   // diagonal regions (weight 1)
    float acc2 = 0.f;   // upper off-diagonal regions (weight 2)
#pragma unroll
    for (int j = 0; j < 8; ++j) {
        if (j < rA) continue;                      // wave-uniform guard
        const int gC = (j << 5) + row;
        const short8 Bm0 = *(const short8*)&xs[gC * XSTR + (half << 3)];
        const short8 Bm1 = *(const short8*)&xs[gC * XSTR + 16 + (half << 3)];
        const short8 Bh  = half ? zfrag : *(const short8*)&eB[gC << 3];

        // row rA: tiles (rA, j) for j >= rA
        f32x16 g = __builtin_amdgcn_mfma_f32_32x32x16_bf16(AhA,  Bh,  zacc, 0, 0, 0);
        g = __builtin_amdgcn_mfma_f32_32x32x16_bf16(AmA0, Bm0, g, 0, 0, 0);
        g = __builtin_amdgcn_mfma_f32_32x32x16_bf16(AmA1, Bm1, g, 0, 0, 0);
        const float s = abs_sum16(g);
        if (j == rA) acc1 += s; else acc2 += s;

        // row rB: tiles (rB, j) for j >= rB (rB >= rA so shares this j range)
        if (j >= rB) {
            f32x16 h = __builtin_amdgcn_mfma_f32_32x32x16_bf16(AhB,  Bh,  zacc, 0, 0, 0);
            h = __builtin_amdgcn_mfma_f32_32x32x16_bf16(AmB0, Bm0, h, 0, 0, 0);
            h = __builtin_amdgcn_mfma_f32_32x32x16_bf16(AmB1, Bm1, h, 0, 0, 0);
            const float s2 = abs_sum16(h);
            if (j == rB) acc1 += s2; else acc2 += s2;
        }
    }
    float a = acc1 + 2.f * acc2;    // full-matrix sum via symmetry

    // block reduction -> ONE plain store per block (no global atomics)
#pragma unroll
    for (int off = 32; off > 0; off >>= 1)
        a += __shfl_down(a, off, 64);
    if (lane == 0) red[w] = a;
    __syncthreads();
    if (t == 0)
        partial[b] = (red[0] + red[1]) + (red[2] + red[3]);
}

__global__ __launch_bounds__(256)
void reduce_kernel(const float* __restrict__ partial, float* __restrict__ out,
                   int n, float scale)
{
    __shared__ float red[4];
    float a = 0.f;
    for (int i = threadIdx.x; i < n; i += 256) a += partial[i];
#pragma unroll
    for (int off = 32; off > 0; off >>= 1)
        a += __shfl_down(a, off, 64);
    const int lane = threadIdx.x & 63, w = threadIdx.x >> 6;
    if (lane == 0) red[w] = a;
    __syncthreads();
    if (threadIdx.x == 0)
        out[0] = ((red[0] + red[1]) + (red[2] + red[3])) * scale;
}

extern "C" void kernel_launch(void* const* d_in, const int* in_sizes, int n_in,
                              void* d_out, int out_size, void* d_ws, size_t ws_size,
                              hipStream_t stream) {
    const float* msi   = (const float*)d_in[0];
    const float* he    = (const float*)d_in[1];
    const int*   i_idx = (const int*)d_in[2];
    const int*   j_idx = (const int*)d_in[3];
    const int    NB    = in_sizes[2];
    float*       out   = (float*)d_out;
    float*       part  = (float*)d_ws;        // NB floats of scratch

    const float scale = 1.0f / ((float)(PSZ * PSZ) * (float)(NB / 5));
    corr_loss_kernel<<<NB, 256, 0, stream>>>(msi, he, i_idx, j_idx, part);
    reduce_kernel<<<1, 256, 0, stream>>>(part, out, NB, scale);
}